// Round 19
// baseline (80.594 us; speedup 1.0000x reference)
//
#include <hip/hip_runtime.h>

typedef float f32x2 __attribute__((ext_vector_type(2)));
typedef float f32x4 __attribute__((ext_vector_type(4)));

#define N_SUB 10
#define SUBSP 10
#define SC 0.125f  // 2^-3 pre-scale (s=3 squarings, order-8 PS)
#define LROW 17    // stage stride: 16 floats/lane/pass + 1 pad (odd -> 17l
                   // mod 32 bijective -> uniform 8 words/bank, no swizzle)

#define LO2(v4) __builtin_shufflevector(v4, v4, 0, 1)
#define HI2(v4) __builtin_shufflevector(v4, v4, 2, 3)

// ================= packed-FP32 primitives =================
// MEASURED (r6-r12): v_pk_fma_f32 = 4 cyc (2 FMA/lane) = scalar FLOP rate.
// pk kept: halves instr count; op_sel broadcast kills splat movs.
//   _L: both result halves use src0.lo    _H: both use src0.hi
#define PK_FMA_L(d, x, y) \
  asm("v_pk_fma_f32 %0, %1, %2, %0 op_sel:[0,0,0] op_sel_hi:[0,1,1]" \
      : "+v"(d) : "v"(x), "v"(y))
#define PK_FMA_H(d, x, y) \
  asm("v_pk_fma_f32 %0, %1, %2, %0 op_sel:[1,0,0] op_sel_hi:[1,1,1]" \
      : "+v"(d) : "v"(x), "v"(y))
#define PK_MUL_L(d, x, y) \
  asm("v_pk_mul_f32 %0, %1, %2 op_sel:[0,0] op_sel_hi:[0,1]" \
      : "=v"(d) : "v"(x), "v"(y))
#define PK_MUL_H(d, x, y) \
  asm("v_pk_mul_f32 %0, %1, %2 op_sel:[1,0] op_sel_hi:[1,1]" \
      : "=v"(d) : "v"(x), "v"(y))

// ---- 8x8 matrix = 32 NAMED f32x2 SSA values: row r, chunk j (cols 2j,2j+1).
// No arrays -> no scratch demotion (round-3 lesson: arrays = 460MB spill).
#define DECLR(M, r) f32x2 M##r##0, M##r##1, M##r##2, M##r##3
#define DECLM(M) \
  DECLR(M,0); DECLR(M,1); DECLR(M,2); DECLR(M,3); \
  DECLR(M,4); DECLR(M,5); DECLR(M,6); DECLR(M,7)

// Z[r][2j..2j+1] = sum_k X[r][k] * Y[k][2j..2j+1]; X element k lives in
// chunk k/2, half k%2 -> alternate _L/_H broadcasts.
#define MMCH(Z, X, Y, r, j)                  \
  PK_MUL_L(Z##r##j, X##r##0, Y##0##j);       \
  PK_FMA_H(Z##r##j, X##r##0, Y##1##j);       \
  PK_FMA_L(Z##r##j, X##r##1, Y##2##j);       \
  PK_FMA_H(Z##r##j, X##r##1, Y##3##j);       \
  PK_FMA_L(Z##r##j, X##r##2, Y##4##j);       \
  PK_FMA_H(Z##r##j, X##r##2, Y##5##j);       \
  PK_FMA_L(Z##r##j, X##r##3, Y##6##j);       \
  PK_FMA_H(Z##r##j, X##r##3, Y##7##j);
#define MMROW(Z, X, Y, r) \
  MMCH(Z,X,Y,r,0) MMCH(Z,X,Y,r,1) MMCH(Z,X,Y,r,2) MMCH(Z,X,Y,r,3)
#define MM(Z, X, Y)                                          \
  MMROW(Z,X,Y,0) MMROW(Z,X,Y,1) MMROW(Z,X,Y,2) MMROW(Z,X,Y,3) \
  MMROW(Z,X,Y,4) MMROW(Z,X,Y,5) MMROW(Z,X,Y,6) MMROW(Z,X,Y,7)

// ================= ROUND-19 build: direct global->VGPR basis =================
// r11-r18 loaded the basis via SMEM: out-of-order returns force 10 serial
// FULL lgkmcnt(0) drains per wave -- the dominant uncovered per-wave stall
// at ~2 resident waves/SIMD. VMEM (global_load_dwordx4) is counted/in-order
// (vmcnt) -> the compiler software-pipelines loads across the pk-FMA stream
// automatically. Wave-uniform addresses = 1 transaction/load, L1-broadcast;
// 2.5KB/g basis is L1-resident after first touch. (Never tested before:
// rounds <=10 went global->LDS->VGPR, 11-18 went SMEM.)
#define BROWG(k, r, h) (*(const f32x4*)(bp + (k)*64 + (r)*8 + (h)*4))
// One row-step covers basis matrices 2t,2t+1: zz={z_2t,z_2t+1}*SC, A gets
// lo-half broadcast vs B-matrix 2t, hi-half vs 2t+1.
#define BLD2ROW(r, t, F0, F1) {                              \
    f32x4 u0 = BROWG(2*(t),   r, 0), u1 = BROWG(2*(t),   r, 1); \
    f32x4 w0 = BROWG(2*(t)+1, r, 0), w1 = BROWG(2*(t)+1, r, 1); \
    F0(A##r##0, zz, LO2(u0)); F1(A##r##0, zz, LO2(w0));      \
    F0(A##r##1, zz, HI2(u0)); F1(A##r##1, zz, HI2(w0));      \
    F0(A##r##2, zz, LO2(u1)); F1(A##r##2, zz, LO2(w1));      \
    F0(A##r##3, zz, HI2(u1)); F1(A##r##3, zz, HI2(w1)); }
#define BLD2MAT(t, F0, F1)                                   \
  BLD2ROW(0,t,F0,F1) BLD2ROW(1,t,F0,F1) BLD2ROW(2,t,F0,F1)   \
  BLD2ROW(3,t,F0,F1) BLD2ROW(4,t,F0,F1) BLD2ROW(5,t,F0,F1)   \
  BLD2ROW(6,t,F0,F1) BLD2ROW(7,t,F0,F1)

// P = ca*X + cb*Y ; P = cc*X + Q
#define LCROW(P, X, Y, ca, cb, r)                            \
  P##r##0 = (ca)*X##r##0 + (cb)*Y##r##0;                     \
  P##r##1 = (ca)*X##r##1 + (cb)*Y##r##1;                     \
  P##r##2 = (ca)*X##r##2 + (cb)*Y##r##2;                     \
  P##r##3 = (ca)*X##r##3 + (cb)*Y##r##3;
#define LC(P, X, Y, ca, cb)                                  \
  LCROW(P,X,Y,ca,cb,0) LCROW(P,X,Y,ca,cb,1) LCROW(P,X,Y,ca,cb,2) \
  LCROW(P,X,Y,ca,cb,3) LCROW(P,X,Y,ca,cb,4) LCROW(P,X,Y,ca,cb,5) \
  LCROW(P,X,Y,ca,cb,6) LCROW(P,X,Y,ca,cb,7)
#define AXROW(P, X, Q, cc, r)                                \
  P##r##0 = (cc)*X##r##0 + Q##r##0;                          \
  P##r##1 = (cc)*X##r##1 + Q##r##1;                          \
  P##r##2 = (cc)*X##r##2 + Q##r##2;                          \
  P##r##3 = (cc)*X##r##3 + Q##r##3;
#define AXPY(P, X, Q, cc)                                    \
  AXROW(P,X,Q,cc,0) AXROW(P,X,Q,cc,1) AXROW(P,X,Q,cc,2)      \
  AXROW(P,X,Q,cc,3) AXROW(P,X,Q,cc,4) AXROW(P,X,Q,cc,5)      \
  AXROW(P,X,Q,cc,6) AXROW(P,X,Q,cc,7)

// diag (r,r): chunk r/2, element r%2
#define ADD_DIAG(M, c)                                       \
  M##00[0] += (c); M##10[1] += (c); M##21[0] += (c); M##31[1] += (c); \
  M##42[0] += (c); M##52[1] += (c); M##63[0] += (c); M##73[1] += (c);

// ---- Chunked LDS stage (r17, proven): 4 passes, 4352B footprint,
// coalesced stores (256 full-64B-line transactions/wave vs 1024 scattered
// 16B pre-r16 -- that change was -17%).
#define SPW(j)    ((f32x4*)&lds[lane * LROW + (j) * 4])
#define SPR(M, j) ((f32x4*)&lds[(M) * LROW + (j) * 4])
#define DRAIN1(p, t) {                                       \
    const int M = (t) * 16 + (lane >> 2);                    \
    f32x4 v = *SPR(M, qd);                                   \
    *(f32x4*)(out + (((size_t)(B0 + M) * N_SUB + g) << 6)    \
              + ((4 * (p) + qd) << 2)) = v; }
#define PASS(p, ra, rb) {                                    \
    f32x4 w;                                                 \
    w = __builtin_shufflevector(Q##ra##0, Q##ra##1, 0,1,2,3); *SPW(0) = w; \
    w = __builtin_shufflevector(Q##ra##2, Q##ra##3, 0,1,2,3); *SPW(1) = w; \
    w = __builtin_shufflevector(Q##rb##0, Q##rb##1, 0,1,2,3); *SPW(2) = w; \
    w = __builtin_shufflevector(Q##rb##2, Q##rb##3, 0,1,2,3); *SPW(3) = w; \
    DRAIN1(p, 0) DRAIN1(p, 1) DRAIN1(p, 2) DRAIN1(p, 3) }

// exp(M) (M pre-scaled by 2^-3): ORDER-8 Paterson-Stockmeyer + 3 squarings
// (7 MMs, error ~2e-6 rel). Result lands in Q, drained via 4 PASSes.
#define EXPM_PASSES(M) {                                     \
    DECLM(S); MM(S, M, M)                                    \
    DECLM(P); LC(P, S, M, c8, c7) ADD_DIAG(P, c6)            \
    DECLM(Q); MM(Q, S, P)                                    \
    AXPY(P, M, Q, c5) ADD_DIAG(P, c4)                        \
    MM(Q, S, P)                                              \
    AXPY(P, M, Q, c3) ADD_DIAG(P, c2)                        \
    MM(Q, S, P)                                              \
    AXPY(P, M, Q, 1.0f) ADD_DIAG(P, 1.0f)                    \
    MM(Q, P, P) MM(P, Q, Q) MM(Q, P, P)                      \
    PASS(0, 0, 1) PASS(1, 2, 3) PASS(2, 4, 5) PASS(3, 6, 7) }

// waves_per_eu(2,4): proven-safe codegen (r10-r17: VGPR 108-128, no spill;
// allocator law: budget = 256/min, so min>=3 force-fits and spills).
__global__ __launch_bounds__(64)
__attribute__((amdgpu_waves_per_eu(2, 4)))
void lie_expm_kernel(const float* __restrict__ z,
                     const float* __restrict__ basis,
                     float* __restrict__ out) {
  __shared__ __align__(16) float lds[64 * LROW];  // 4352 B
  const int lane = threadIdx.x & 63;
  const int qd = lane & 3;
  const int W = blockIdx.x;            // wave id == block id
  const int g  = W % N_SUB;            // uniform by construction
  const int B0 = (W / N_SUB) * 64;     // first batch row of this wave

  const float* bp = basis + g * (SUBSP * 64);   // wave-uniform base

  // z row for (b, g): 10 floats at z + b*100 + g*10 (8B-aligned), as 5 pairs.
  const int b = B0 + lane;
  const float* zrow = z + (size_t)b * (N_SUB * SUBSP) + g * SUBSP;
  const f32x2 zp0 = *(const f32x2*)(zrow + 0) * SC;
  const f32x2 zp1 = *(const f32x2*)(zrow + 2) * SC;
  const f32x2 zp2 = *(const f32x2*)(zrow + 4) * SC;
  const f32x2 zp3 = *(const f32x2*)(zrow + 6) * SC;
  const f32x2 zp4 = *(const f32x2*)(zrow + 8) * SC;

  // ---- Build A = sum_k z_k * B_k (pre-scaled): 160 global_load_dwordx4
  // (wave-uniform, L1-broadcast, compiler-pipelined via counted vmcnt)
  // + 320 pk-FMA. k even -> pair.lo (_L), k odd -> pair.hi (_H).
  DECLM(A);
  { const f32x2 zz = zp0; BLD2MAT(0, PK_MUL_L, PK_FMA_H) }
  { const f32x2 zz = zp1; BLD2MAT(1, PK_FMA_L, PK_FMA_H) }
  { const f32x2 zz = zp2; BLD2MAT(2, PK_FMA_L, PK_FMA_H) }
  { const f32x2 zz = zp3; BLD2MAT(3, PK_FMA_L, PK_FMA_H) }
  { const f32x2 zz = zp4; BLD2MAT(4, PK_FMA_L, PK_FMA_H) }

  const float c2 = 0.5f, c3 = 1.0f / 6.0f, c4 = 1.0f / 24.0f,
              c5 = 1.0f / 120.0f, c6 = 1.0f / 720.0f,
              c7 = 1.0f / 5040.0f, c8 = 1.0f / 40320.0f;

  // ---- expm; result drained in 4 chunked, coalesced passes.
  EXPM_PASSES(A);
}

extern "C" void kernel_launch(void* const* d_in, const int* in_sizes, int n_in,
                              void* d_out, int out_size, void* d_ws, size_t ws_size,
                              hipStream_t stream) {
  const float* z = (const float*)d_in[0];
  const float* basis = (const float*)d_in[1];
  float* out = (float*)d_out;

  const int batch = in_sizes[0] / (N_SUB * SUBSP);  // 65536
  const int grid = batch / 64 * N_SUB;              // 10240 1-wave blocks

  lie_expm_kernel<<<grid, 64, 0, stream>>>(z, basis, out);
}

// Round 20
// 73.882 us; speedup vs baseline: 1.0909x; 1.0909x over previous
//
#include <hip/hip_runtime.h>

typedef float f32x2 __attribute__((ext_vector_type(2)));
typedef float f32x4 __attribute__((ext_vector_type(4)));
typedef float f32x16 __attribute__((ext_vector_type(16)));

#define N_SUB 10
#define SUBSP 10
#define SC 0.125f  // 2^-3 pre-scale (s=3 squarings, order-8 PS)
#define LROW 17    // stage stride: 16 floats/lane/pass + 1 pad (odd -> 17l
                   // mod 32 bijective -> uniform 8 words/bank, no swizzle)

// ================= scalar-pipe basis loads =================
// One subgroup g per WAVE -> basis is wave-uniform -> stream via SGPRs on
// the scalar pipe. SMEM returns out-of-order -> full lgkmcnt(0) drains only.
// MEASURED LEDGER (r19): basis via LDS = 91-104us, via VMEM-direct = 80.6us,
// via SMEM = 74.6us (best) -- SMEM's drains cost less than VMEM's issue
// traffic or LDS's pipe serialization at ~2 resident waves/SIMD.
#define SLOAD16(dst, base, imm) \
  asm volatile("s_load_dwordx16 %0, %1, %2" \
               : "=s"(dst) : "s"(base), "i"(imm))
// waitcnt DEFINES the loaded regs ("+s") so consumers are dataflow-ordered
// behind it (rule-18-proof: no reliance on "memory" clobber ordering).
#define SWAIT4(a, b, c, d) \
  asm volatile("s_waitcnt lgkmcnt(0)" \
               : "+s"(a), "+s"(b), "+s"(c), "+s"(d))

// even-aligned SGPR pair (2j, 2j+1) extracted from an x16 scalar vector
#define SPAIR(V, j) __builtin_shufflevector(V, V, 2*(j), 2*(j)+1)

// ================= packed-FP32 primitives =================
// MEASURED (r6-r12): v_pk_fma_f32 = 4 cyc (2 FMA/lane) = scalar FLOP rate.
// pk kept: halves instr count; op_sel broadcast kills splat movs.
#define PKB_FMA_L(d, zp, sp) \
  asm("v_pk_fma_f32 %0, %1, %2, %0 op_sel:[0,0,0] op_sel_hi:[0,1,1]" \
      : "+v"(d) : "v"(zp), "s"(sp))
#define PKB_FMA_H(d, zp, sp) \
  asm("v_pk_fma_f32 %0, %1, %2, %0 op_sel:[1,0,0] op_sel_hi:[1,1,1]" \
      : "+v"(d) : "v"(zp), "s"(sp))
#define PKB_MUL_L(d, zp, sp) \
  asm("v_pk_mul_f32 %0, %1, %2 op_sel:[0,0] op_sel_hi:[0,1]" \
      : "=v"(d) : "v"(zp), "s"(sp))
#define PK_FMA_L(d, x, y) \
  asm("v_pk_fma_f32 %0, %1, %2, %0 op_sel:[0,0,0] op_sel_hi:[0,1,1]" \
      : "+v"(d) : "v"(x), "v"(y))
#define PK_FMA_H(d, x, y) \
  asm("v_pk_fma_f32 %0, %1, %2, %0 op_sel:[1,0,0] op_sel_hi:[1,1,1]" \
      : "+v"(d) : "v"(x), "v"(y))
#define PK_MUL_L(d, x, y) \
  asm("v_pk_mul_f32 %0, %1, %2 op_sel:[0,0] op_sel_hi:[0,1]" \
      : "=v"(d) : "v"(x), "v"(y))

// ---- 8x8 matrix = 32 NAMED f32x2 SSA values: row r, chunk j (cols 2j,2j+1).
// No arrays -> no scratch demotion (round-3 lesson: arrays = 460MB spill).
#define DECLR(M, r) f32x2 M##r##0, M##r##1, M##r##2, M##r##3
#define DECLM(M) \
  DECLR(M,0); DECLR(M,1); DECLR(M,2); DECLR(M,3); \
  DECLR(M,4); DECLR(M,5); DECLR(M,6); DECLR(M,7)

// Z[r][2j..2j+1] = sum_k X[r][k] * Y[k][2j..2j+1]; X element k lives in
// chunk k/2, half k%2 -> alternate _L/_H broadcasts.
#define MMCH(Z, X, Y, r, j)                  \
  PK_MUL_L(Z##r##j, X##r##0, Y##0##j);       \
  PK_FMA_H(Z##r##j, X##r##0, Y##1##j);       \
  PK_FMA_L(Z##r##j, X##r##1, Y##2##j);       \
  PK_FMA_H(Z##r##j, X##r##1, Y##3##j);       \
  PK_FMA_L(Z##r##j, X##r##2, Y##4##j);       \
  PK_FMA_H(Z##r##j, X##r##2, Y##5##j);       \
  PK_FMA_L(Z##r##j, X##r##3, Y##6##j);       \
  PK_FMA_H(Z##r##j, X##r##3, Y##7##j);
#define MMROW(Z, X, Y, r) \
  MMCH(Z,X,Y,r,0) MMCH(Z,X,Y,r,1) MMCH(Z,X,Y,r,2) MMCH(Z,X,Y,r,3)
#define MM(Z, X, Y)                                          \
  MMROW(Z,X,Y,0) MMROW(Z,X,Y,1) MMROW(Z,X,Y,2) MMROW(Z,X,Y,3) \
  MMROW(Z,X,Y,4) MMROW(Z,X,Y,5) MMROW(Z,X,Y,6) MMROW(Z,X,Y,7)

// ---- Build: one k-step = 64 basis floats s_loaded into 4 x16 SGPR vectors.
#define BLDK2(F, Kv, ra, rb)                                  \
  F(A##ra##0, zz, SPAIR(Kv,0)); F(A##ra##1, zz, SPAIR(Kv,1)); \
  F(A##ra##2, zz, SPAIR(Kv,2)); F(A##ra##3, zz, SPAIR(Kv,3)); \
  F(A##rb##0, zz, SPAIR(Kv,4)); F(A##rb##1, zz, SPAIR(Kv,5)); \
  F(A##rb##2, zz, SPAIR(Kv,6)); F(A##rb##3, zz, SPAIR(Kv,7));
#define KSTEP(koff, F)                                        \
  {                                                           \
    f32x16 K0, K1, K2, K3;                                    \
    SLOAD16(K0, bp, (koff)*256 + 0);                          \
    SLOAD16(K1, bp, (koff)*256 + 64);                         \
    SLOAD16(K2, bp, (koff)*256 + 128);                        \
    SLOAD16(K3, bp, (koff)*256 + 192);                        \
    SWAIT4(K0, K1, K2, K3);                                   \
    BLDK2(F, K0, 0, 1) BLDK2(F, K1, 2, 3)                     \
    BLDK2(F, K2, 4, 5) BLDK2(F, K3, 6, 7)                     \
  }

// P = ca*X + cb*Y ; P = cc*X + Q
#define LCROW(P, X, Y, ca, cb, r)                            \
  P##r##0 = (ca)*X##r##0 + (cb)*Y##r##0;                     \
  P##r##1 = (ca)*X##r##1 + (cb)*Y##r##1;                     \
  P##r##2 = (ca)*X##r##2 + (cb)*Y##r##2;                     \
  P##r##3 = (ca)*X##r##3 + (cb)*Y##r##3;
#define LC(P, X, Y, ca, cb)                                  \
  LCROW(P,X,Y,ca,cb,0) LCROW(P,X,Y,ca,cb,1) LCROW(P,X,Y,ca,cb,2) \
  LCROW(P,X,Y,ca,cb,3) LCROW(P,X,Y,ca,cb,4) LCROW(P,X,Y,ca,cb,5) \
  LCROW(P,X,Y,ca,cb,6) LCROW(P,X,Y,ca,cb,7)
#define AXROW(P, X, Q, cc, r)                                \
  P##r##0 = (cc)*X##r##0 + Q##r##0;                          \
  P##r##1 = (cc)*X##r##1 + Q##r##1;                          \
  P##r##2 = (cc)*X##r##2 + Q##r##2;                          \
  P##r##3 = (cc)*X##r##3 + Q##r##3;
#define AXPY(P, X, Q, cc)                                    \
  AXROW(P,X,Q,cc,0) AXROW(P,X,Q,cc,1) AXROW(P,X,Q,cc,2)      \
  AXROW(P,X,Q,cc,3) AXROW(P,X,Q,cc,4) AXROW(P,X,Q,cc,5)      \
  AXROW(P,X,Q,cc,6) AXROW(P,X,Q,cc,7)

// diag (r,r): chunk r/2, element r%2
#define ADD_DIAG(M, c)                                       \
  M##00[0] += (c); M##10[1] += (c); M##21[0] += (c); M##31[1] += (c); \
  M##42[0] += (c); M##52[1] += (c); M##63[0] += (c); M##73[1] += (c);

// ---- Chunked LDS stage (r17, proven best): 4 passes, 4352B footprint,
// coalesced stores: each store instr covers 16 FULL 64B lines -> 256
// transactions/wave vs 1024 scattered 16B pre-r16 (that change was -17%).
// Stride 17 floats: conflict-free both sides (odd -> bijective mod 32).
// Per-wave LDS ops are in-order; pass-to-pass reuse same-address -> no
// barriers needed (1-wave block).
#define SPW(j)    ((f32x4*)&lds[lane * LROW + (j) * 4])
#define SPR(M, j) ((f32x4*)&lds[(M) * LROW + (j) * 4])
#define DRAIN1(p, t) {                                       \
    const int M = (t) * 16 + (lane >> 2);                    \
    f32x4 v = *SPR(M, qd);                                   \
    *(f32x4*)(out + (((size_t)(B0 + M) * N_SUB + g) << 6)    \
              + ((4 * (p) + qd) << 2)) = v; }
#define PASS(p, ra, rb) {                                    \
    f32x4 w;                                                 \
    w = __builtin_shufflevector(Q##ra##0, Q##ra##1, 0,1,2,3); *SPW(0) = w; \
    w = __builtin_shufflevector(Q##ra##2, Q##ra##3, 0,1,2,3); *SPW(1) = w; \
    w = __builtin_shufflevector(Q##rb##0, Q##rb##1, 0,1,2,3); *SPW(2) = w; \
    w = __builtin_shufflevector(Q##rb##2, Q##rb##3, 0,1,2,3); *SPW(3) = w; \
    DRAIN1(p, 0) DRAIN1(p, 1) DRAIN1(p, 2) DRAIN1(p, 3) }

// exp(M) (M pre-scaled by 2^-3): ORDER-8 Paterson-Stockmeyer + 3 squarings
// (7 MMs, error ~2e-6 rel). Result lands in Q, drained via 4 PASSes.
#define EXPM_PASSES(M) {                                     \
    DECLM(S); MM(S, M, M)                                    \
    DECLM(P); LC(P, S, M, c8, c7) ADD_DIAG(P, c6)            \
    DECLM(Q); MM(Q, S, P)                                    \
    AXPY(P, M, Q, c5) ADD_DIAG(P, c4)                        \
    MM(Q, S, P)                                              \
    AXPY(P, M, Q, c3) ADD_DIAG(P, c2)                        \
    MM(Q, S, P)                                              \
    AXPY(P, M, Q, 1.0f) ADD_DIAG(P, 1.0f)                    \
    MM(Q, P, P) MM(P, Q, Q) MM(Q, P, P)                      \
    PASS(0, 0, 1) PASS(1, 2, 3) PASS(2, 4, 5) PASS(3, 6, 7) }

// ROUND-20: exact revert to round-17 (74.58us, session best). r19's VMEM
// basis regressed to 80.6us. waves_per_eu(2,4): proven-safe codegen
// (VGPR ~112, zero spill); r18 showed default attr is identical.
__global__ __launch_bounds__(64)
__attribute__((amdgpu_waves_per_eu(2, 4)))
void lie_expm_kernel(const float* __restrict__ z,
                     const float* __restrict__ basis,
                     float* __restrict__ out) {
  __shared__ __align__(16) float lds[64 * LROW];  // 4352 B
  const int lane = threadIdx.x & 63;
  const int qd = lane & 3;
  const int W = blockIdx.x;            // wave id == block id
  const int g  = W % N_SUB;            // uniform (SGPR) by construction
  const int B0 = (W / N_SUB) * 64;     // first batch row of this wave

  const float* bp = basis + g * (SUBSP * 64);   // uniform -> SGPR pair

  // z row for (b, g): 10 floats at z + b*100 + g*10 (8B-aligned), as 5 pairs.
  const int b = B0 + lane;
  const float* zrow = z + (size_t)b * (N_SUB * SUBSP) + g * SUBSP;
  const f32x2 zv0 = *(const f32x2*)(zrow + 0) * SC;
  const f32x2 zv1 = *(const f32x2*)(zrow + 2) * SC;
  const f32x2 zv2 = *(const f32x2*)(zrow + 4) * SC;
  const f32x2 zv3 = *(const f32x2*)(zrow + 6) * SC;
  const f32x2 zv4 = *(const f32x2*)(zrow + 8) * SC;

  // ---- Build A = sum_k z_k * B_k (pre-scaled): 40 s_loads + 320 pk-FMA.
  DECLM(A);
  { const f32x2 zz = zv0; KSTEP(0, PKB_MUL_L) }
  { const f32x2 zz = zv0; KSTEP(1, PKB_FMA_H) }
  { const f32x2 zz = zv1; KSTEP(2, PKB_FMA_L) }
  { const f32x2 zz = zv1; KSTEP(3, PKB_FMA_H) }
  { const f32x2 zz = zv2; KSTEP(4, PKB_FMA_L) }
  { const f32x2 zz = zv2; KSTEP(5, PKB_FMA_H) }
  { const f32x2 zz = zv3; KSTEP(6, PKB_FMA_L) }
  { const f32x2 zz = zv3; KSTEP(7, PKB_FMA_H) }
  { const f32x2 zz = zv4; KSTEP(8, PKB_FMA_L) }
  { const f32x2 zz = zv4; KSTEP(9, PKB_FMA_H) }

  const float c2 = 0.5f, c3 = 1.0f / 6.0f, c4 = 1.0f / 24.0f,
              c5 = 1.0f / 120.0f, c6 = 1.0f / 720.0f,
              c7 = 1.0f / 5040.0f, c8 = 1.0f / 40320.0f;

  // ---- expm; result drained in 4 chunked, coalesced passes.
  EXPM_PASSES(A);
}

extern "C" void kernel_launch(void* const* d_in, const int* in_sizes, int n_in,
                              void* d_out, int out_size, void* d_ws, size_t ws_size,
                              hipStream_t stream) {
  const float* z = (const float*)d_in[0];
  const float* basis = (const float*)d_in[1];
  float* out = (float*)d_out;

  const int batch = in_sizes[0] / (N_SUB * SUBSP);  // 65536
  const int grid = batch / 64 * N_SUB;              // 10240 1-wave blocks

  lie_expm_kernel<<<grid, 64, 0, stream>>>(z, basis, out);
}